// Round 3
// baseline (9351.262 us; speedup 1.0000x reference)
//
#include <hip/hip_runtime.h>
#include <hip/hip_bf16.h>

#define NL 4
#define NB 4
#define NS 512
#define NH 1024
#define NV 32000
#define RING 8
#define SUBS (NS * NB)

typedef unsigned int u32;
typedef unsigned short u16;
typedef unsigned long long u64;
typedef __attribute__((ext_vector_type(8))) __bf16 vbf16x8;
typedef __attribute__((ext_vector_type(8))) u16   vu16x8;
typedef __attribute__((ext_vector_type(4))) u32   vu32x4;
typedef __attribute__((ext_vector_type(4))) float vf32x4;

template<int N> struct ic { static constexpr int value = N; };

__device__ __forceinline__ u16 f2bf(float f) {
    u32 x = __builtin_bit_cast(u32, f);
    x += 0x7FFFu + ((x >> 16) & 1u);
    return (u16)(x >> 16);
}
__device__ __forceinline__ float softplus_f(float x) {
    return fmaxf(x, 0.0f) + log1pf(expf(-fabsf(x)));
}
__device__ __forceinline__ int aload(const int* p) {
    return __hip_atomic_load(p, __ATOMIC_RELAXED, __HIP_MEMORY_SCOPE_AGENT);
}
__device__ __forceinline__ u64 aload64(const u64* p) {
    return __hip_atomic_load(p, __ATOMIC_RELAXED, __HIP_MEMORY_SCOPE_AGENT);
}
__device__ __forceinline__ void astore(int* p, int v) {
    __hip_atomic_store(p, v, __ATOMIC_RELAXED, __HIP_MEMORY_SCOPE_AGENT);
}
__device__ __forceinline__ void astore32(u32* p, u32 v) {
    __hip_atomic_store(p, v, __ATOMIC_RELAXED, __HIP_MEMORY_SCOPE_AGENT);
}

// poll per-slice flags lane-parallel: lane i checks slice i's counter
__device__ __forceinline__ void do_poll(int layer, int s3, const int* pf, int lane) {
    const int t3 = s3 >> 2, b3 = s3 & 3;
    const bool n1 = (t3 >= 1);      // own-layer h(t3-1) published
    const bool n2 = (layer > 0);    // prev-layer in(t3) published
    if (!(n1 || n2)) return;
    const int* a1 = pf + ((layer * NB + b3) << 6) + lane;
    const int* a2 = pf + (((layer - 1) * NB + b3) << 6) + lane;
    for (int it = 0; it < (1 << 20); ++it) {
        bool ok = true;
        if (n1) ok &= (aload(a1) >= t3);
        if (n2) ok &= (aload(a2) >= t3 + 1);
        if (__all((int)ok)) return;
        __builtin_amdgcn_s_sleep(1);
    }
}

// issue sc1 ring loads for sub-step s2 into (hv, iv); idx = 0..255
__device__ __forceinline__ void do_load(int layer, int s2, int idx,
        const int* ids, const float* emb, const u32* ring, u64& hv, u64& iv) {
    const int t2 = s2 >> 2, b2 = s2 & 3;
    if (t2 == 0) hv = 0;
    else hv = aload64((const u64*)(ring + ((((size_t)layer * NB + b2) * RING + ((t2 - 1) & 7)) << 9)) + idx);
    if (layer == 0) {
        const int v = ids[b2 * NS + t2];
        vf32x4 f = *(const vf32x4*)(emb + (size_t)v * NH + 4 * idx);
        iv = (u64)f2bf(f[0]) | ((u64)f2bf(f[1]) << 16) | ((u64)f2bf(f[2]) << 32) | ((u64)f2bf(f[3]) << 48);
    } else {
        iv = aload64((const u64*)(ring + ((((size_t)(layer - 1) * NB + b2) * RING + (t2 & 7)) << 9)) + idx);
    }
}

#define APAD 8
#define ASTR (NH + APAD)

// 256 blocks x 320 threads. layer = bid&3, slice = bid>>2 (64 slices x 16 rows).
// Waves 0-3: MFMA (matrix w: 0=Ws,1=Us,2=twh,3=twu), weights resident in VGPRs.
// Wave 4: publisher (ring stores + vmcnt(0) + per-slice flag store) off critical path.
// Batch-staggered sub-steps s=4t+b; poll lookahead 3, load lookahead 2.
__global__ __launch_bounds__(320, 1) void lnn_recur(
    const int* __restrict__ ids, const float* __restrict__ emb,
    const float* __restrict__ Ws, const float* __restrict__ Us,
    const float* __restrict__ bsv, const float* __restrict__ twh,
    const float* __restrict__ twu, const float* __restrict__ tbv,
    const float* __restrict__ lambda_p,
    int* pf, int* ack, u32* ring, u16* out16, float* hT_out)
{
    __shared__ __align__(16) u16 act_hp[NB][ASTR];
    __shared__ __align__(16) u16 act_in[NB][ASTR];
    __shared__ float cross[2][4][16];
    __shared__ u32 pubw[2][8];
    __shared__ float bias_a[16], bias_t[16];

    const int bid   = blockIdx.x;
    const int layer = bid & 3;
    const int slice = bid >> 2;
    const int j0    = slice << 4;
    const int tid   = threadIdx.x;
    const int wave  = tid >> 6;
    const int lane  = tid & 63;
    const int idx   = tid;                   // waves 0-3: 0..255

    // ---- resident weight fragments (waves 0-3) ----
    const int jr = j0 + (lane & 15);
    const int kb = (lane >> 4) * 8;
    vbf16x8 wfrag[32];
    if (wave < 4) {
        const float* msel = (wave == 0) ? Ws : (wave == 1) ? Us : (wave == 2) ? twh : twu;
        const float* mat  = msel + (size_t)layer * NH * NH;
#pragma unroll
        for (int c = 0; c < 32; ++c) {
            const float* s = mat + (size_t)jr * NH + c * 32 + kb;
            vu16x8 t8;
#pragma unroll
            for (int e = 0; e < 8; ++e) t8[e] = f2bf(s[e]);
            wfrag[c] = __builtin_bit_cast(vbf16x8, t8);
        }
    }
    if (tid < 16) {
        bias_a[tid] = bsv[layer * NH + j0 + tid];
        bias_t[tid] = tbv[layer * NH + j0 + tid];
    }
    const float lam = softplus_f(lambda_p[0]);
    float h0 = 0.f, h1 = 0.f, h2 = 0.f, h3 = 0.f;
    u64 hvA = 0, ivA = 0, hvB = 0, ivB = 0;

    // ---- prologue: fill the 3-deep pipeline ----
    if (wave < 4) {
        do_poll(layer, 0, pf, lane);
        do_poll(layer, 1, pf, lane);
        do_load(layer, 0, idx, ids, emb, ring, hvA, ivA);
        do_poll(layer, 2, pf, lane);
        do_load(layer, 1, idx, ids, emb, ring, hvB, ivB);
    }

    auto substep = [&](auto Bc, int t, float& hB, u64& hv, u64& iv) {
        constexpr int B_ = Bc.value;
        constexpr int p_ = B_ & 1;
        const int s_ = 4 * t + B_;
        // B: stage batch row B_ from regs (loaded 2 sub-steps ago)
        if (wave < 4) {
            *(u64*)(((u32*)&act_hp[B_][0]) + 2 * idx) = hv;
            *(u64*)(((u32*)&act_in[B_][0]) + 2 * idx) = iv;
        }
        __syncthreads();   // D
        if (layer > 0 && tid == 0)
            astore(ack + (((layer - 1) * NB + B_) << 6) + slice, t + 1);
        if (wave < 4) {
            // E: MFMA out[j] = sum_k act[B_][k] * M[j][k]
            const u16 (*asrc)[ASTR] = ((wave & 1) == 0) ? act_hp : act_in;
            int ar = lane & 15; if (ar > 3) ar = 3;   // rows 4-15: garbage D rows, unread
            vf32x4 a0 = {0.f,0.f,0.f,0.f}, a1 = a0, a2 = a0, a3 = a0;
#pragma unroll
            for (int c = 0; c < 32; c += 4) {
                a0 = __builtin_amdgcn_mfma_f32_16x16x32_bf16(*(const vbf16x8*)&asrc[ar][(c+0)*32+kb], wfrag[c+0], a0, 0, 0, 0);
                a1 = __builtin_amdgcn_mfma_f32_16x16x32_bf16(*(const vbf16x8*)&asrc[ar][(c+1)*32+kb], wfrag[c+1], a1, 0, 0, 0);
                a2 = __builtin_amdgcn_mfma_f32_16x16x32_bf16(*(const vbf16x8*)&asrc[ar][(c+2)*32+kb], wfrag[c+2], a2, 0, 0, 0);
                a3 = __builtin_amdgcn_mfma_f32_16x16x32_bf16(*(const vbf16x8*)&asrc[ar][(c+3)*32+kb], wfrag[c+3], a3, 0, 0, 0);
            }
            vf32x4 accs = (a0 + a1) + (a2 + a3);
            if (lane < 16) cross[p_][wave][lane] = accs[B_];   // D row B_ lives in reg B_, lanes 0-15
        } else {
            // wave4: publish sub-step s_-1 (ring stores -> vmcnt(0) -> flag store)
            if (s_ >= 1) {
                const int tp = (B_ == 0) ? t - 1 : t;
                const int bp = (B_ + 3) & 3;
                if (layer < 3 && tp >= RING) {      // ring-slot reuse gate (consumer acks)
                    const int tgt = tp - RING + 1;
                    const int* ap = ack + ((layer * NB + bp) << 6) + lane;
                    for (int it = 0; it < (1 << 20); ++it) {
                        if (__all((int)(aload(ap) >= tgt))) break;
                        __builtin_amdgcn_s_sleep(1);
                    }
                }
                if (lane < 8) {
                    u32 pk = pubw[p_ ^ 1][lane];
                    astore32(ring + ((((size_t)layer * NB + bp) * RING + (tp & 7)) << 9) + slice * 8 + lane, pk);
                }
                asm volatile("s_waitcnt vmcnt(0)" ::: "memory");
                if (lane == 0) astore(pf + ((layer * NB + bp) << 6) + slice, tp + 1);
            }
        }
        __syncthreads();   // F
        // G: finalize (wave0 lanes 0-15)
        if (wave == 0 && lane < 16) {
            const float sa = cross[p_][0][lane] + cross[p_][1][lane] + bias_a[lane];
            const float st = cross[p_][2][lane] + cross[p_][3][lane] + bias_t[lane];
            const float tau = softplus_f(st) + 0.01f;
            const float av  = tanhf(sa);
            float dx = lam * (av - hB / tau);
            dx = fminf(10.0f, fmaxf(-10.0f, dx));
            hB = fmaf(0.1f, dx, hB);
            const u16 hb = f2bf(hB);
            ((u16*)&pubw[p_][0])[lane] = hb;
            if (layer == 3) out16[((size_t)B_ * NS + t) * NH + j0 + lane] = hb;   // plain store
            if (t == NS - 1) hT_out[((size_t)layer * NB + B_) * NH + j0 + lane] = hB;
        }
        // H: poll s_+3, reload this reg set for s_+2
        if (wave < 4) {
            if (s_ + 3 < SUBS) do_poll(layer, s_ + 3, pf, lane);
            if (s_ + 2 < SUBS) do_load(layer, s_ + 2, idx, ids, emb, ring, hv, iv);
        }
    };

    for (int t = 0; t < NS; ++t) {
        substep(ic<0>{}, t, h0, hvA, ivA);
        substep(ic<1>{}, t, h1, hvB, ivB);
        substep(ic<2>{}, t, h2, hvA, ivA);
        substep(ic<3>{}, t, h3, hvB, ivB);
    }
    // epilogue: publish final sub-step (t=511, b=3); pub parity = 2047&1 = 1
    __syncthreads();
    if (wave == 4) {
        const int tp = NS - 1, bp = 3;
        if (layer < 3) {
            const int tgt = tp - RING + 1;
            const int* ap = ack + ((layer * NB + bp) << 6) + lane;
            for (int it = 0; it < (1 << 20); ++it) {
                if (__all((int)(aload(ap) >= tgt))) break;
                __builtin_amdgcn_s_sleep(1);
            }
        }
        if (lane < 8)
            astore32(ring + ((((size_t)layer * NB + bp) * RING + (tp & 7)) << 9) + slice * 8 + lane, pubw[1][lane]);
        asm volatile("s_waitcnt vmcnt(0)" ::: "memory");
        if (lane == 0) astore(pf + ((layer * NB + bp) << 6) + slice, tp + 1);
    }
}

// ---------------- projection GEMM: C[2048][32000] = A[2048][1024](bf16) * W[32000][1024]^T + b ----
#define BM 128
#define BN 128
#define BK 32
#define KSTEPS (NH / BK)
#define LSTR (BK + 8)

__global__ __launch_bounds__(256, 1) void proj_gemm(
    const u16* __restrict__ A, const float* __restrict__ Bw,
    const float* __restrict__ bias, float* __restrict__ C)
{
    __shared__ __align__(16) u16 Asm[2][BM][LSTR];
    __shared__ __align__(16) u16 Bsm[2][BN][LSTR];

    const int tid  = threadIdx.x;
    const int wave = tid >> 6, lane = tid & 63;
    const int wr = wave >> 1, wc = wave & 1;

    const int nwg = gridDim.x;
    const int id  = blockIdx.x;
    const int q = nwg >> 3, r = nwg & 7;
    const int x = id & 7, o = id >> 3;
    const int wg = (x < r ? x * (q + 1) : r * (q + 1) + (x - r) * q) + o;
    const int m0 = (wg & 15) * BM;
    const int n0 = (wg >> 4) * BN;

    const int srow  = tid >> 1;
    const int shalf = tid & 1;
    const u16*   agp = A  + (size_t)(m0 + srow) * NH + shalf * 16;
    const float* bgp = Bw + (size_t)(n0 + srow) * NH + shalf * 16;

    vf32x4 zed = {0.f, 0.f, 0.f, 0.f};
    vf32x4 acc[4][4];
#pragma unroll
    for (int m = 0; m < 4; ++m)
#pragma unroll
        for (int n = 0; n < 4; ++n) acc[m][n] = zed;

    vu32x4 areg0, areg1; vf32x4 breg0, breg1, breg2, breg3;
    auto load_tile = [&](int kt) {
        const u16* ap = agp + kt * BK;
        areg0 = *(const vu32x4*)ap;
        areg1 = *(const vu32x4*)(ap + 8);
        const float* bp = bgp + kt * BK;
        breg0 = *(const vf32x4*)bp;       breg1 = *(const vf32x4*)(bp + 4);
        breg2 = *(const vf32x4*)(bp + 8); breg3 = *(const vf32x4*)(bp + 12);
    };
    auto write_tile = [&](int buf) {
        u16* ad = &Asm[buf][srow][shalf * 16];
        *(vu32x4*)ad = areg0; *(vu32x4*)(ad + 8) = areg1;
        float fb[16];
        *(vf32x4*)&fb[0] = breg0; *(vf32x4*)&fb[4]  = breg1;
        *(vf32x4*)&fb[8] = breg2; *(vf32x4*)&fb[12] = breg3;
        vu16x8 v0, v1;
#pragma unroll
        for (int e = 0; e < 8; ++e) { v0[e] = f2bf(fb[e]); v1[e] = f2bf(fb[8 + e]); }
        u16* bd = &Bsm[buf][srow][shalf * 16];
        *(vu16x8*)bd = v0; *(vu16x8*)(bd + 8) = v1;
    };

    load_tile(0); write_tile(0);
    __syncthreads();

    const int fr = lane & 15;
    const int fk = (lane >> 4) * 8;
    for (int kt = 0; kt < KSTEPS; ++kt) {
        const int cur = kt & 1;
        if (kt + 1 < KSTEPS) load_tile(kt + 1);
        vbf16x8 afr[4], bfr[4];
#pragma unroll
        for (int m = 0; m < 4; ++m)
            afr[m] = *(const vbf16x8*)&Asm[cur][wr * 64 + m * 16 + fr][fk];
#pragma unroll
        for (int n = 0; n < 4; ++n)
            bfr[n] = *(const vbf16x8*)&Bsm[cur][wc * 64 + n * 16 + fr][fk];
#pragma unroll
        for (int m = 0; m < 4; ++m)
#pragma unroll
            for (int n = 0; n < 4; ++n)
                acc[m][n] = __builtin_amdgcn_mfma_f32_16x16x32_bf16(afr[m], bfr[n], acc[m][n], 0, 0, 0);
        if (kt + 1 < KSTEPS) write_tile(cur ^ 1);
        __syncthreads();
    }

    const int cc = lane & 15;
    const int cr = (lane >> 4) * 4;
#pragma unroll
    for (int m = 0; m < 4; ++m) {
#pragma unroll
        for (int n = 0; n < 4; ++n) {
            const int gc = n0 + wc * 64 + n * 16 + cc;
            const float bval = bias[gc];
            float* cp = C + (size_t)(m0 + wr * 64 + m * 16 + cr) * NV + gc;
#pragma unroll
            for (int r = 0; r < 4; ++r)
                cp[(size_t)r * NV] = acc[m][n][r] + bval;
        }
    }
}

extern "C" void kernel_launch(void* const* d_in, const int* in_sizes, int n_in,
                              void* d_out, int out_size, void* d_ws, size_t ws_size,
                              hipStream_t stream) {
    const int*   ids = (const int*)  d_in[0];
    const float* emb = (const float*)d_in[1];
    const float* pw  = (const float*)d_in[2];
    const float* pb  = (const float*)d_in[3];
    const float* lam = (const float*)d_in[4];
    const float* Ws  = (const float*)d_in[5];
    const float* Us  = (const float*)d_in[6];
    const float* bsv = (const float*)d_in[7];
    const float* twh = (const float*)d_in[8];
    const float* twu = (const float*)d_in[9];
    const float* tbv = (const float*)d_in[10];

    char* ws = (char*)d_ws;
    int* pf       = (int*)ws;                       // 4*4*64*4 = 4 KB
    int* ack      = (int*)(ws + 4096);              // 3*4*64*4 = 3 KB
    u32* ring     = (u32*)(ws + 8192);              // 4*4*8*512*4 = 256 KB
    u16* out_bf16 = (u16*)(ws + 8192 + 262144);     // 2048*1024*2 = 4 MB

    float* logits = (float*)d_out;
    float* hT     = logits + (size_t)NB * NS * NV;

    hipMemsetAsync(pf, 0, 8192, stream);            // flags + acks, every call
    lnn_recur<<<dim3(256), dim3(320), 0, stream>>>(ids, emb, Ws, Us, bsv, twh, twu, tbv, lam,
                                                   pf, ack, ring, out_bf16, hT);
    proj_gemm<<<dim3((NV / BN) * ((NB * NS) / BM)), dim3(256), 0, stream>>>(out_bf16, pw, pb, logits);
}

// Round 4
// 2809.261 us; speedup vs baseline: 3.3287x; 3.3287x over previous
//
#include <hip/hip_runtime.h>
#include <hip/hip_bf16.h>

#define NL 4
#define NB 4
#define NS 512
#define NH 1024
#define NV 32000
#define RING 16

typedef unsigned int u32;
typedef unsigned short u16;
typedef __attribute__((ext_vector_type(8))) __bf16 vbf16x8;
typedef __attribute__((ext_vector_type(8))) u16   vu16x8;
typedef __attribute__((ext_vector_type(4))) u32   vu32x4;
typedef __attribute__((ext_vector_type(4))) float vf32x4;

__device__ __forceinline__ u16 f2bf(float f) {
    u32 x = __builtin_bit_cast(u32, f);
    x += 0x7FFFu + ((x >> 16) & 1u);
    return (u16)(x >> 16);
}
__device__ __forceinline__ float softplus_f(float x) {
    return fmaxf(x, 0.0f) + log1pf(expf(-fabsf(x)));
}
__device__ __forceinline__ int aloadi(const int* p) {
    return __hip_atomic_load(p, __ATOMIC_RELAXED, __HIP_MEMORY_SCOPE_AGENT);
}
__device__ __forceinline__ u32 aload32(const u32* p) {
    return __hip_atomic_load(p, __ATOMIC_RELAXED, __HIP_MEMORY_SCOPE_AGENT);
}
__device__ __forceinline__ void astorei(int* p, int v) {
    __hip_atomic_store(p, v, __ATOMIC_RELAXED, __HIP_MEMORY_SCOPE_AGENT);
}
__device__ __forceinline__ void astore32(u32* p, u32 v) {
    __hip_atomic_store(p, v, __ATOMIC_RELAXED, __HIP_MEMORY_SCOPE_AGENT);
}

#define APAD 8
#define ASTR (NH + APAD)

// 256 blocks x 256 threads (round-2 structure). layer = bid&3, slice = bid>>2.
// Handoff: each h scalar published as ONE dword (bf16<<16 | seq) — data IS the
// flag. Consumers poll their own data dwords; no flag hop, no RMW, no vmcnt ack.
__global__ __launch_bounds__(256, 1) void lnn_recur(
    const int* __restrict__ ids, const float* __restrict__ emb,
    const float* __restrict__ Ws, const float* __restrict__ Us,
    const float* __restrict__ bsv, const float* __restrict__ twh,
    const float* __restrict__ twu, const float* __restrict__ tbv,
    const float* __restrict__ lambda_p,
    int* ack, u32* ring, u16* out16, float* hT_out)
{
    __shared__ __align__(16) u16 act_hp[5][ASTR];   // rows 0-3 = batch, row 4 = zeros
    __shared__ __align__(16) u16 act_in[5][ASTR];
    __shared__ float cross[4][16][4];               // [mat][j][b]
    __shared__ float bias_a[16], bias_t[16];

    const int bid   = blockIdx.x;
    const int layer = bid & 3;
    const int slice = bid >> 2;
    const int j0    = slice << 4;
    const int tid   = threadIdx.x;
    const int wave  = tid >> 6;
    const int lane  = tid & 63;

    // ---- resident weight fragments: wave w owns matrix w (0=Ws,1=Us,2=twh,3=twu) ----
    const float* msel = (wave == 0) ? Ws : (wave == 1) ? Us : (wave == 2) ? twh : twu;
    const float* mat  = msel + (size_t)layer * NH * NH;
    const int jr = j0 + (lane & 15);        // B col = output row j
    const int kb = (lane >> 4) * 8;         // k offset within 32-chunk
    vbf16x8 wfrag[32];
#pragma unroll
    for (int c = 0; c < 32; ++c) {
        const float* s = mat + (size_t)jr * NH + c * 32 + kb;
        vu16x8 t8;
#pragma unroll
        for (int e = 0; e < 8; ++e) t8[e] = f2bf(s[e]);
        wfrag[c] = __builtin_bit_cast(vbf16x8, t8);
    }

    for (int i = tid; i < ASTR; i += 256) { act_hp[4][i] = 0; act_in[4][i] = 0; }
    if (tid < 16) {
        bias_a[tid] = bsv[layer * NH + j0 + tid];
        bias_t[tid] = tbv[layer * NH + j0 + tid];
    }
    const float lam = softplus_f(lambda_p[0]);
    float hreg = 0.0f;                       // wave0: (j = lane&15, b = lane>>4)
    const int lm1 = (layer > 0) ? layer - 1 : 0;

    for (int t = 0; t < NS; ++t) {
        // ---- A: fused poll+load (each thread owns 16 h + 16 in dwords) ----
        {
            const int b = wave;
            const u32* hb_ = ring + (((size_t)(layer * NB + b)) * RING + ((t - 1) & (RING - 1))) * NH + lane;
            const u32* ib_ = ring + (((size_t)(lm1   * NB + b)) * RING + ( t      & (RING - 1))) * NH + lane;
            u32 hv[16], iv[16];
            u32 pendH = (t > 0)     ? 0xFFFFu : 0u;
            u32 pendI = (layer > 0) ? 0xFFFFu : 0u;
            const u32 seqH = (u32)t, seqI = (u32)(t + 1);
            const bool needAck = (wave == 0) && (layer < 3) && (t >= RING);
            const int  ackTgt  = t - RING + 1;
            const int* ackp    = ack + (layer + 1) * 64 + lane;
            bool ackok = !needAck;

            if (t == 0) {
#pragma unroll
                for (int i = 0; i < 16; ++i) hv[i] = 0;
            }
            if (layer == 0) {
                const int v = ids[b * NS + t];
                const float* er = emb + (size_t)v * NH + lane;
#pragma unroll
                for (int i = 0; i < 16; ++i) iv[i] = ((u32)f2bf(er[64 * i])) << 16;
            }
            for (int it = 0; it < (1 << 20); ++it) {
#pragma unroll
                for (int i = 0; i < 16; ++i) if (pendH & (1u << i)) hv[i] = aload32(hb_ + 64 * i);
#pragma unroll
                for (int i = 0; i < 16; ++i) if (pendI & (1u << i)) iv[i] = aload32(ib_ + 64 * i);
#pragma unroll
                for (int i = 0; i < 16; ++i) if ((pendH & (1u << i)) && ((hv[i] & 0xFFFFu) == seqH)) pendH &= ~(1u << i);
#pragma unroll
                for (int i = 0; i < 16; ++i) if ((pendI & (1u << i)) && ((iv[i] & 0xFFFFu) == seqI)) pendI &= ~(1u << i);
                if (needAck && !ackok) ackok = (aloadi(ackp) >= ackTgt);
                const bool done = (pendH == 0u) & (pendI == 0u) & (ackok | !needAck);
                if (__all((int)done)) break;
                __builtin_amdgcn_s_sleep(2);
            }
            // stage to LDS (u16 writes: 2 lanes/bank = free)
#pragma unroll
            for (int i = 0; i < 16; ++i) {
                act_hp[b][64 * i + lane] = (u16)(hv[i] >> 16);
                act_in[b][64 * i + lane] = (u16)(iv[i] >> 16);
            }
        }
        __syncthreads();
        if (tid == 0 && layer > 0) astorei(ack + layer * 64 + slice, t + 1);   // consumed in(t)

        // ---- B: MFMA out[j,b] = sum_k act[b,k] * M[j,k]; 4 accumulators ----
        {
            const u16 (*asrc)[ASTR] = ((wave & 1) == 0) ? act_hp : act_in;
            int ar = lane & 15; if (ar > 4) ar = 4;   // rows 5-15 read the zero row
            vf32x4 a0 = {0.f,0.f,0.f,0.f}, a1 = a0, a2 = a0, a3 = a0;
#pragma unroll
            for (int c = 0; c < 32; c += 4) {
                a0 = __builtin_amdgcn_mfma_f32_16x16x32_bf16(*(const vbf16x8*)&asrc[ar][(c+0)*32+kb], wfrag[c+0], a0, 0, 0, 0);
                a1 = __builtin_amdgcn_mfma_f32_16x16x32_bf16(*(const vbf16x8*)&asrc[ar][(c+1)*32+kb], wfrag[c+1], a1, 0, 0, 0);
                a2 = __builtin_amdgcn_mfma_f32_16x16x32_bf16(*(const vbf16x8*)&asrc[ar][(c+2)*32+kb], wfrag[c+2], a2, 0, 0, 0);
                a3 = __builtin_amdgcn_mfma_f32_16x16x32_bf16(*(const vbf16x8*)&asrc[ar][(c+3)*32+kb], wfrag[c+3], a3, 0, 0, 0);
            }
            vf32x4 acc = (a0 + a1) + (a2 + a3);
            if (lane < 16) {
#pragma unroll
                for (int r = 0; r < 4; ++r) cross[wave][lane][r] = acc[r];
            }
        }
        __syncthreads();

        // ---- C: finalize + publish (wave 0); single relaxed dword store per scalar ----
        if (wave == 0) {
            const int j = lane & 15, b = lane >> 4;
            const float sa = cross[0][j][b] + cross[1][j][b] + bias_a[j];
            const float st = cross[2][j][b] + cross[3][j][b] + bias_t[j];
            const float tau = softplus_f(st) + 0.01f;
            const float av  = tanhf(sa);
            float dx = lam * (av - hreg / tau);
            dx = fminf(10.0f, fmaxf(-10.0f, dx));
            hreg = fmaf(0.1f, dx, hreg);
            const u16 hb = f2bf(hreg);
            const u32 pk = ((u32)hb << 16) | (u32)(t + 1);
            astore32(ring + (((size_t)(layer * NB + b)) * RING + (t & (RING - 1))) * NH + j0 + j, pk);
            if (layer == 3) out16[((size_t)b * NS + t) * NH + j0 + j] = hb;
            if (t == NS - 1) hT_out[((size_t)layer * NB + b) * NH + j0 + j] = hreg;
        }
    }
}

// ---------------- projection GEMM: C[2048][32000] = A[2048][1024](bf16) * W[32000][1024]^T + b ----
#define BM 128
#define BN 128
#define BK 32
#define KSTEPS (NH / BK)
#define LSTR (BK + 8)

__global__ __launch_bounds__(256, 1) void proj_gemm(
    const u16* __restrict__ A, const float* __restrict__ Bw,
    const float* __restrict__ bias, float* __restrict__ C)
{
    __shared__ __align__(16) u16 Asm[2][BM][LSTR];
    __shared__ __align__(16) u16 Bsm[2][BN][LSTR];

    const int tid  = threadIdx.x;
    const int wave = tid >> 6, lane = tid & 63;
    const int wr = wave >> 1, wc = wave & 1;

    const int nwg = gridDim.x;
    const int id  = blockIdx.x;
    const int q = nwg >> 3, r = nwg & 7;
    const int x = id & 7, o = id >> 3;
    const int wg = (x < r ? x * (q + 1) : r * (q + 1) + (x - r) * q) + o;
    const int m0 = (wg & 15) * BM;
    const int n0 = (wg >> 4) * BN;

    const int srow  = tid >> 1;
    const int shalf = tid & 1;
    const u16*   agp = A  + (size_t)(m0 + srow) * NH + shalf * 16;
    const float* bgp = Bw + (size_t)(n0 + srow) * NH + shalf * 16;

    vf32x4 zed = {0.f, 0.f, 0.f, 0.f};
    vf32x4 acc[4][4];
#pragma unroll
    for (int m = 0; m < 4; ++m)
#pragma unroll
        for (int n = 0; n < 4; ++n) acc[m][n] = zed;

    vu32x4 areg0, areg1; vf32x4 breg0, breg1, breg2, breg3;
    auto load_tile = [&](int kt) {
        const u16* ap = agp + kt * BK;
        areg0 = *(const vu32x4*)ap;
        areg1 = *(const vu32x4*)(ap + 8);
        const float* bp = bgp + kt * BK;
        breg0 = *(const vf32x4*)bp;       breg1 = *(const vf32x4*)(bp + 4);
        breg2 = *(const vf32x4*)(bp + 8); breg3 = *(const vf32x4*)(bp + 12);
    };
    auto write_tile = [&](int buf) {
        u16* ad = &Asm[buf][srow][shalf * 16];
        *(vu32x4*)ad = areg0; *(vu32x4*)(ad + 8) = areg1;
        float fb[16];
        *(vf32x4*)&fb[0] = breg0; *(vf32x4*)&fb[4]  = breg1;
        *(vf32x4*)&fb[8] = breg2; *(vf32x4*)&fb[12] = breg3;
        vu16x8 v0, v1;
#pragma unroll
        for (int e = 0; e < 8; ++e) { v0[e] = f2bf(fb[e]); v1[e] = f2bf(fb[8 + e]); }
        u16* bd = &Bsm[buf][srow][shalf * 16];
        *(vu16x8*)bd = v0; *(vu16x8*)(bd + 8) = v1;
    };

    load_tile(0); write_tile(0);
    __syncthreads();

    const int fr = lane & 15;
    const int fk = (lane >> 4) * 8;
    for (int kt = 0; kt < KSTEPS; ++kt) {
        const int cur = kt & 1;
        if (kt + 1 < KSTEPS) load_tile(kt + 1);
        vbf16x8 afr[4], bfr[4];
#pragma unroll
        for (int m = 0; m < 4; ++m)
            afr[m] = *(const vbf16x8*)&Asm[cur][wr * 64 + m * 16 + fr][fk];
#pragma unroll
        for (int n = 0; n < 4; ++n)
            bfr[n] = *(const vbf16x8*)&Bsm[cur][wc * 64 + n * 16 + fr][fk];
#pragma unroll
        for (int m = 0; m < 4; ++m)
#pragma unroll
            for (int n = 0; n < 4; ++n)
                acc[m][n] = __builtin_amdgcn_mfma_f32_16x16x32_bf16(afr[m], bfr[n], acc[m][n], 0, 0, 0);
        if (kt + 1 < KSTEPS) write_tile(cur ^ 1);
        __syncthreads();
    }

    const int cc = lane & 15;
    const int cr = (lane >> 4) * 4;
#pragma unroll
    for (int m = 0; m < 4; ++m) {
#pragma unroll
        for (int n = 0; n < 4; ++n) {
            const int gc = n0 + wc * 64 + n * 16 + cc;
            const float bval = bias[gc];
            float* cp = C + (size_t)(m0 + wr * 64 + m * 16 + cr) * NV + gc;
#pragma unroll
            for (int r = 0; r < 4; ++r)
                cp[(size_t)r * NV] = acc[m][n][r] + bval;
        }
    }
}

extern "C" void kernel_launch(void* const* d_in, const int* in_sizes, int n_in,
                              void* d_out, int out_size, void* d_ws, size_t ws_size,
                              hipStream_t stream) {
    const int*   ids = (const int*)  d_in[0];
    const float* emb = (const float*)d_in[1];
    const float* pw  = (const float*)d_in[2];
    const float* pb  = (const float*)d_in[3];
    const float* lam = (const float*)d_in[4];
    const float* Ws  = (const float*)d_in[5];
    const float* Us  = (const float*)d_in[6];
    const float* bsv = (const float*)d_in[7];
    const float* twh = (const float*)d_in[8];
    const float* twu = (const float*)d_in[9];
    const float* tbv = (const float*)d_in[10];

    char* ws = (char*)d_ws;
    u32* ring     = (u32*)ws;                          // 4*4*16*1024*4 = 1 MB
    int* ack      = (int*)(ws + (1 << 20));            // 4*64*4 = 1 KB (pad to 4 KB)
    u16* out_bf16 = (u16*)(ws + (1 << 20) + 4096);     // 2048*1024*2 = 4 MB

    float* logits = (float*)d_out;
    float* hT     = logits + (size_t)NB * NS * NV;

    hipMemsetAsync(ws, 0, (1 << 20) + 4096, stream);   // ring seqs + acks, every call
    lnn_recur<<<dim3(256), dim3(256), 0, stream>>>(ids, emb, Ws, Us, bsv, twh, twu, tbv, lam,
                                                   ack, ring, out_bf16, hT);
    proj_gemm<<<dim3((NV / BN) * ((NB * NS) / BM)), dim3(256), 0, stream>>>(out_bf16, pw, pb, logits);
}